// Round 4
// baseline (240.137 us; speedup 1.0000x reference)
//
#include <hip/hip_runtime.h>
#include <math.h>

#define NPROT 50000
#define NPROT_PAD 50048
#define EPPI 500000
#define NPAIR 4096
#define SLAB 64

typedef __attribute__((ext_vector_type(8))) __bf16 bf16x8;
typedef __attribute__((ext_vector_type(4))) __bf16 bf16x4;
typedef __attribute__((ext_vector_type(4))) float floatx4;

// ---------- prep: Xb bf16 cast, Bw pack, P/biasC (parallel), cnt[]=0 ----------
__global__ void k_prep(const float* __restrict__ x,
                       const float* __restrict__ Wl, const float* __restrict__ Wr,
                       const float* __restrict__ linW, const float* __restrict__ linb,
                       const float* __restrict__ bWl, const float* __restrict__ bWr,
                       const float* __restrict__ bb,
                       __bf16* __restrict__ Xb, __bf16* __restrict__ Bw,
                       float* __restrict__ P, float* __restrict__ biasC,
                       int* __restrict__ cnt) {
    __shared__ float sP[10];
    int b = blockIdx.x, t = threadIdx.x;
    if (b < 6250) {
        int i = b * 256 + t;              // float4 index over 50000*32
        int row = i >> 5, k4 = (i & 31) << 2;
        float4 v = *(const float4*)(x + (size_t)row * 128 + k4);
        bf16x4 o; o[0] = (__bf16)v.x; o[1] = (__bf16)v.y; o[2] = (__bf16)v.z; o[3] = (__bf16)v.w;
        *(bf16x4*)(Xb + (size_t)row * 128 + k4) = o;
    } else if (b < 6506) {
        // Bw[h][k]: k<128 -> aWl, else aWr  (bf16)
        int idx = (b - 6250) * 256 + t;   // 65536
        int h = idx >> 8, k = idx & 255;
        float v = (k < 128) ? Wl[h * 128 + k] : Wr[h * 128 + (k - 128)];
        Bw[idx] = (__bf16)v;
    } else if (b < 6762) {
        // P[h][0..3] via 128-wide parallel dot; block handles output column h
        int h = b - 6506;
        int lane = t & 63, wave = t >> 6;
        float v1 = 0, v2 = 0, u1 = 0, u2 = 0, c = 0;
        if (t < 128) {
            float w1 = linW[t], w2 = linW[128 + t];
            float wl = bWl[t * 256 + h], wr = bWr[t * 256 + h];
            v1 = w1 * wl; v2 = w2 * wl; u1 = w1 * wr; u2 = w2 * wr;
            if (h == 0) c = (w1 + w2) * bb[t];
        }
#pragma unroll
        for (int m = 1; m < 64; m <<= 1) {
            v1 += __shfl_xor(v1, m, 64); v2 += __shfl_xor(v2, m, 64);
            u1 += __shfl_xor(u1, m, 64); u2 += __shfl_xor(u2, m, 64);
            c  += __shfl_xor(c, m, 64);
        }
        if (lane == 0 && wave < 2) {
            sP[wave * 5 + 0] = v1; sP[wave * 5 + 1] = v2;
            sP[wave * 5 + 2] = u1; sP[wave * 5 + 3] = u2;
            sP[wave * 5 + 4] = c;
        }
        __syncthreads();
        if (t == 0) {
            P[h * 4 + 0] = sP[0] + sP[5]; P[h * 4 + 1] = sP[1] + sP[6];
            P[h * 4 + 2] = sP[2] + sP[7]; P[h * 4 + 3] = sP[3] + sP[8];
            if (h == 0) *biasC = linb[0] + sP[4] + sP[9];
        }
    } else {
        int i = (b - 6762) * 256 + t;
        if (i < NPROT) cnt[i] = 0;
    }
}

// ---------- adjacency: atomic slab buckets (CSR without the scan) ----------
__global__ void k_link(const int* __restrict__ src, const int* __restrict__ dst,
                       int* __restrict__ cnt, int* __restrict__ slab) {
    int e = blockIdx.x * 256 + threadIdx.x;
    if (e < EPPI) {
        int d = dst[e];
        int pos = atomicAdd(&cnt[d], 1);
        if (pos < SLAB) slab[(size_t)d * SLAB + pos] = src[e];
    }
}

// ---------- layer-1 neighbor mean: slab gather Xb -> Am (bf16) ----------
// quarter-wave (16 lanes x bf16x8) per node; 8 independent row loads in flight.
__global__ void k_agg(const __bf16* __restrict__ Xb, const int* __restrict__ cnt,
                      const int* __restrict__ slab, __bf16* __restrict__ Am) {
    int wave = threadIdx.x >> 6, lane = threadIdx.x & 63;
    int q = lane >> 4, sl = lane & 15;
    int node = blockIdx.x * 16 + wave * 4 + q;
    if (node >= NPROT) return;
    float a[8];
#pragma unroll
    for (int e8 = 0; e8 < 8; e8++) a[e8] = 0.f;
    const __bf16* base = Xb + (size_t)sl * 8;
    int c = cnt[node];
    if (c > SLAB) c = SLAB;
    const int* sp = slab + (size_t)node * SLAB;
    int j = 0;
    for (; j + 8 <= c; j += 8) {
        int4 sa = *(const int4*)(sp + j);
        int4 sb = *(const int4*)(sp + j + 4);
        bf16x8 v0 = *(const bf16x8*)(base + (size_t)sa.x * 128);
        bf16x8 v1 = *(const bf16x8*)(base + (size_t)sa.y * 128);
        bf16x8 v2 = *(const bf16x8*)(base + (size_t)sa.z * 128);
        bf16x8 v3 = *(const bf16x8*)(base + (size_t)sa.w * 128);
        bf16x8 v4 = *(const bf16x8*)(base + (size_t)sb.x * 128);
        bf16x8 v5 = *(const bf16x8*)(base + (size_t)sb.y * 128);
        bf16x8 v6 = *(const bf16x8*)(base + (size_t)sb.z * 128);
        bf16x8 v7 = *(const bf16x8*)(base + (size_t)sb.w * 128);
#pragma unroll
        for (int e8 = 0; e8 < 8; e8++)
            a[e8] += (float)v0[e8] + (float)v1[e8] + (float)v2[e8] + (float)v3[e8]
                   + (float)v4[e8] + (float)v5[e8] + (float)v6[e8] + (float)v7[e8];
    }
    for (; j < c; j++) {
        int s = sp[j];
        bf16x8 v = *(const bf16x8*)(base + (size_t)s * 128);
#pragma unroll
        for (int e8 = 0; e8 < 8; e8++) a[e8] += (float)v[e8];
    }
    float iv = 1.0f / (float)(c > 1 ? c : 1);
    bf16x8 o;
#pragma unroll
    for (int e8 = 0; e8 < 8; e8++) o[e8] = (__bf16)(a[e8] * iv);
    *(bf16x8*)(Am + (size_t)node * 128 + sl * 8) = o;
}

// ---------- GEMM z = [Am|Xb] @ Bw^T (+ab), relu, project onto P -> y[node][4] ----------
// Barrier-free, LDS-free: B is 128 KB (L2/L1-resident, every block rereads it),
// so fragments are read straight from global. No __syncthreads, no vmcnt(0)
// drain; latency hidden by 32 independent B-loads per chunk + MFMA overlap.
// 64 rows/block, 2 waves x 32 rows.
__global__ __launch_bounds__(128) void k_gemm(const __bf16* __restrict__ Am,
                                              const __bf16* __restrict__ Xb,
                                              const __bf16* __restrict__ Bw,
                                              const float* __restrict__ ab,
                                              const float* __restrict__ P,
                                              float* __restrict__ y) {
    int tid = threadIdx.x;
    int wave = tid >> 6, lane = tid & 63;
    int r = lane & 15, quad = lane >> 4;
    int row0 = blockIdx.x * 64 + wave * 32;

    // A fragments: kk 0..3 -> mean (Am), kk 4..7 -> own (Xb)
    bf16x8 afrag[2][8];
#pragma unroll
    for (int g = 0; g < 2; g++) {
        const __bf16* mp = Am + (size_t)(row0 + g * 16 + r) * 128 + quad * 8;
        const __bf16* op = Xb + (size_t)(row0 + g * 16 + r) * 128 + quad * 8;
#pragma unroll
        for (int kk = 0; kk < 4; kk++) {
            afrag[g][kk]     = *(const bf16x8*)(mp + kk * 32);
            afrag[g][4 + kk] = *(const bf16x8*)(op + kk * 32);
        }
    }

    float part[2][4][4] = {{{0.f}}};

#pragma unroll 1
    for (int chunk = 0; chunk < 4; chunk++) {
        floatx4 acc[2][4];
#pragma unroll
        for (int g = 0; g < 2; g++)
#pragma unroll
            for (int t = 0; t < 4; t++) acc[g][t] = (floatx4){0.f, 0.f, 0.f, 0.f};
        const __bf16* bp = Bw + (size_t)(chunk * 64 + r) * 256 + quad * 8;
#pragma unroll
        for (int kk = 0; kk < 8; kk++) {
#pragma unroll
            for (int t = 0; t < 4; t++) {
                bf16x8 bf = *(const bf16x8*)(bp + (size_t)t * 16 * 256 + kk * 32);
                acc[0][t] = __builtin_amdgcn_mfma_f32_16x16x32_bf16(afrag[0][kk], bf, acc[0][t], 0, 0, 0);
                acc[1][t] = __builtin_amdgcn_mfma_f32_16x16x32_bf16(afrag[1][kk], bf, acc[1][t], 0, 0, 0);
            }
        }

        // epilogue: h = relu(z + ab[col]); accumulate projection onto P
#pragma unroll
        for (int t = 0; t < 4; t++) {
            int col = chunk * 64 + t * 16 + r;
            float bias = ab[col];
            float4 pv = *(const float4*)(P + col * 4);
#pragma unroll
            for (int g = 0; g < 2; g++)
#pragma unroll
                for (int rr = 0; rr < 4; rr++) {
                    float h = acc[g][t][rr] + bias;
                    h = h > 0.f ? h : 0.f;
                    part[g][rr][0] += h * pv.x; part[g][rr][1] += h * pv.y;
                    part[g][rr][2] += h * pv.z; part[g][rr][3] += h * pv.w;
                }
        }
    }

    // reduce over the 16 col-lanes (r); store 32 rows per wave
#pragma unroll
    for (int m = 1; m < 16; m <<= 1)
#pragma unroll
        for (int g = 0; g < 2; g++)
#pragma unroll
            for (int rr = 0; rr < 4; rr++)
#pragma unroll
                for (int j = 0; j < 4; j++)
                    part[g][rr][j] += __shfl_xor(part[g][rr][j], m, 64);
    if (r == 0) {
#pragma unroll
        for (int g = 0; g < 2; g++)
#pragma unroll
            for (int rr = 0; rr < 4; rr++) {
                int row = row0 + g * 16 + quad * 4 + rr;
                float4 o;
                o.x = part[g][rr][0]; o.y = part[g][rr][1];
                o.z = part[g][rr][2]; o.w = part[g][rr][3];
                *(float4*)(y + (size_t)row * 4) = o;
            }
    }
}

// ---------- head: per masked node, slab-walk sum of scalar projections ----------
__global__ void k_head(const int* __restrict__ mask, const int* __restrict__ cnt,
                       const int* __restrict__ slab, const float* __restrict__ y,
                       const float* __restrict__ biasC, float* __restrict__ out) {
    int tid = blockIdx.x * 256 + threadIdx.x;
    int p = tid >> 1, side = tid & 1;
    float res = 0.f;
    if (p < NPAIR) {
        int node = mask[p * 2 + side];
        int c = cnt[node];
        if (c > SLAB) c = SLAB;
        const int* sp = slab + (size_t)node * SLAB;
        float s = 0.f;
        int j = 0;
        for (; j + 4 <= c; j += 4) {
            int4 sa = *(const int4*)(sp + j);
            s += y[(size_t)sa.x * 4 + side];
            s += y[(size_t)sa.y * 4 + side];
            s += y[(size_t)sa.z * 4 + side];
            s += y[(size_t)sa.w * 4 + side];
        }
        for (; j < c; j++) {
            int si = sp[j];
            s += y[(size_t)si * 4 + side];
        }
        float iv = 1.0f / (float)(c > 1 ? c : 1);
        res = s * iv + y[(size_t)node * 4 + 2 + side];
    }
    float other = __shfl_xor(res, 1, 64);
    if (p < NPAIR && side == 0) {
        float z = res + other + *biasC;
        out[p] = 1.f / (1.f + expf(-z));
    }
}

extern "C" void kernel_launch(void* const* d_in, const int* in_sizes, int n_in,
                              void* d_out, int out_size, void* d_ws, size_t ws_size,
                              hipStream_t stream) {
    const float* x_protein = (const float*)d_in[0];
    const float* a_ppi_Wl  = (const float*)d_in[11];
    const float* a_ppi_b   = (const float*)d_in[12];
    const float* a_ppi_Wr  = (const float*)d_in[13];
    const float* b_ppi_Wl  = (const float*)d_in[23];
    const float* b_ppi_b   = (const float*)d_in[24];
    const float* b_ppi_Wr  = (const float*)d_in[25];
    const float* lin_W     = (const float*)d_in[26];
    const float* lin_b     = (const float*)d_in[27];
    const int* ppi_src     = (const int*)d_in[34];
    const int* ppi_dst     = (const int*)d_in[35];
    const int* mask        = (const int*)d_in[36];
    float* out = (float*)d_out;

    char* ws = (char*)d_ws;
    size_t o = 0;
    auto alloc = [&](size_t n) -> char* {
        char* r = ws + o;
        o = (o + n + 511) & ~(size_t)511;
        return r;
    };
    int*    cnt    = (int*)alloc((size_t)NPROT * 4);
    int*    slab   = (int*)alloc((size_t)NPROT * SLAB * 4);
    __bf16* Xb     = (__bf16*)alloc((size_t)NPROT_PAD * 128 * 2);
    __bf16* Am     = (__bf16*)alloc((size_t)NPROT_PAD * 128 * 2);
    __bf16* Bw     = (__bf16*)alloc(256 * 256 * 2);
    float*  P      = (float*)alloc(256 * 4 * 4);
    float*  biasC  = (float*)alloc(4);
    float*  y      = (float*)alloc((size_t)NPROT_PAD * 4 * 4);
    (void)ws_size;

    k_prep<<<6958, 256, 0, stream>>>(x_protein, a_ppi_Wl, a_ppi_Wr, lin_W, lin_b,
                                     b_ppi_Wl, b_ppi_Wr, b_ppi_b,
                                     Xb, Bw, P, biasC, cnt);
    k_link<<<(EPPI + 255) / 256, 256, 0, stream>>>(ppi_src, ppi_dst, cnt, slab);
    k_agg<<<(NPROT + 15) / 16, 256, 0, stream>>>(Xb, cnt, slab, Am);
    k_gemm<<<NPROT_PAD / 64, 128, 0, stream>>>(Am, Xb, Bw, a_ppi_b, P, y);
    k_head<<<(2 * NPAIR + 255) / 256, 256, 0, stream>>>(mask, cnt, slab, y, biasC, out);
}

// Round 5
// 224.966 us; speedup vs baseline: 1.0674x; 1.0674x over previous
//
#include <hip/hip_runtime.h>
#include <math.h>

#define NPROT 50000
#define NPROT_PAD 50048
#define EPPI 500000
#define NPAIR 4096
#define SLAB 64

typedef __attribute__((ext_vector_type(8))) __bf16 bf16x8;
typedef __attribute__((ext_vector_type(4))) __bf16 bf16x4;
typedef __attribute__((ext_vector_type(4))) float floatx4;

// ---------- prep: Xb bf16 cast, Bw pack, P/biasC (parallel), cnt[]=0 ----------
__global__ void k_prep(const float* __restrict__ x,
                       const float* __restrict__ Wl, const float* __restrict__ Wr,
                       const float* __restrict__ linW, const float* __restrict__ linb,
                       const float* __restrict__ bWl, const float* __restrict__ bWr,
                       const float* __restrict__ bb,
                       __bf16* __restrict__ Xb, __bf16* __restrict__ Bw,
                       float* __restrict__ P, float* __restrict__ biasC,
                       int* __restrict__ cnt) {
    __shared__ float sP[10];
    int b = blockIdx.x, t = threadIdx.x;
    if (b < 6250) {
        int i = b * 256 + t;              // float4 index over 50000*32
        int row = i >> 5, k4 = (i & 31) << 2;
        float4 v = *(const float4*)(x + (size_t)row * 128 + k4);
        bf16x4 o; o[0] = (__bf16)v.x; o[1] = (__bf16)v.y; o[2] = (__bf16)v.z; o[3] = (__bf16)v.w;
        *(bf16x4*)(Xb + (size_t)row * 128 + k4) = o;
    } else if (b < 6506) {
        // Bw[h][k]: k<128 -> aWl, else aWr  (bf16)
        int idx = (b - 6250) * 256 + t;   // 65536
        int h = idx >> 8, k = idx & 255;
        float v = (k < 128) ? Wl[h * 128 + k] : Wr[h * 128 + (k - 128)];
        Bw[idx] = (__bf16)v;
    } else if (b < 6762) {
        // P[h][0..3] via 128-wide parallel dot; block handles output column h
        int h = b - 6506;
        int lane = t & 63, wave = t >> 6;
        float v1 = 0, v2 = 0, u1 = 0, u2 = 0, c = 0;
        if (t < 128) {
            float w1 = linW[t], w2 = linW[128 + t];
            float wl = bWl[t * 256 + h], wr = bWr[t * 256 + h];
            v1 = w1 * wl; v2 = w2 * wl; u1 = w1 * wr; u2 = w2 * wr;
            if (h == 0) c = (w1 + w2) * bb[t];
        }
#pragma unroll
        for (int m = 1; m < 64; m <<= 1) {
            v1 += __shfl_xor(v1, m, 64); v2 += __shfl_xor(v2, m, 64);
            u1 += __shfl_xor(u1, m, 64); u2 += __shfl_xor(u2, m, 64);
            c  += __shfl_xor(c, m, 64);
        }
        if (lane == 0 && wave < 2) {
            sP[wave * 5 + 0] = v1; sP[wave * 5 + 1] = v2;
            sP[wave * 5 + 2] = u1; sP[wave * 5 + 3] = u2;
            sP[wave * 5 + 4] = c;
        }
        __syncthreads();
        if (t == 0) {
            P[h * 4 + 0] = sP[0] + sP[5]; P[h * 4 + 1] = sP[1] + sP[6];
            P[h * 4 + 2] = sP[2] + sP[7]; P[h * 4 + 3] = sP[3] + sP[8];
            if (h == 0) *biasC = linb[0] + sP[4] + sP[9];
        }
    } else {
        int i = (b - 6762) * 256 + t;
        if (i < NPROT) cnt[i] = 0;
    }
}

// ---------- adjacency: atomic slab buckets (CSR without the scan) ----------
__global__ void k_link(const int* __restrict__ src, const int* __restrict__ dst,
                       int* __restrict__ cnt, int* __restrict__ slab) {
    int e = blockIdx.x * 256 + threadIdx.x;
    if (e < EPPI) {
        int d = dst[e];
        int pos = atomicAdd(&cnt[d], 1);
        if (pos < SLAB) slab[(size_t)d * SLAB + pos] = src[e];
    }
}

// ---------- layer-1 neighbor mean: slab gather Xb -> Am (bf16) ----------
// quarter-wave (16 lanes x bf16x8) per node; 8/4-wide index loads -> independent
// row gathers in flight, no dependent hops.
__global__ void k_agg(const __bf16* __restrict__ Xb, const int* __restrict__ cnt,
                      const int* __restrict__ slab, __bf16* __restrict__ Am) {
    int wave = threadIdx.x >> 6, lane = threadIdx.x & 63;
    int q = lane >> 4, sl = lane & 15;
    int node = blockIdx.x * 16 + wave * 4 + q;
    if (node >= NPROT) return;
    float a[8];
#pragma unroll
    for (int e8 = 0; e8 < 8; e8++) a[e8] = 0.f;
    const __bf16* base = Xb + (size_t)sl * 8;
    int c = cnt[node];
    if (c > SLAB) c = SLAB;
    const int* sp = slab + (size_t)node * SLAB;
    int j = 0;
    for (; j + 8 <= c; j += 8) {
        int4 sa = *(const int4*)(sp + j);
        int4 sb = *(const int4*)(sp + j + 4);
        bf16x8 v0 = *(const bf16x8*)(base + (size_t)sa.x * 128);
        bf16x8 v1 = *(const bf16x8*)(base + (size_t)sa.y * 128);
        bf16x8 v2 = *(const bf16x8*)(base + (size_t)sa.z * 128);
        bf16x8 v3 = *(const bf16x8*)(base + (size_t)sa.w * 128);
        bf16x8 v4 = *(const bf16x8*)(base + (size_t)sb.x * 128);
        bf16x8 v5 = *(const bf16x8*)(base + (size_t)sb.y * 128);
        bf16x8 v6 = *(const bf16x8*)(base + (size_t)sb.z * 128);
        bf16x8 v7 = *(const bf16x8*)(base + (size_t)sb.w * 128);
#pragma unroll
        for (int e8 = 0; e8 < 8; e8++)
            a[e8] += (float)v0[e8] + (float)v1[e8] + (float)v2[e8] + (float)v3[e8]
                   + (float)v4[e8] + (float)v5[e8] + (float)v6[e8] + (float)v7[e8];
    }
    if (j + 4 <= c) {
        int4 sa = *(const int4*)(sp + j);
        bf16x8 v0 = *(const bf16x8*)(base + (size_t)sa.x * 128);
        bf16x8 v1 = *(const bf16x8*)(base + (size_t)sa.y * 128);
        bf16x8 v2 = *(const bf16x8*)(base + (size_t)sa.z * 128);
        bf16x8 v3 = *(const bf16x8*)(base + (size_t)sa.w * 128);
#pragma unroll
        for (int e8 = 0; e8 < 8; e8++)
            a[e8] += (float)v0[e8] + (float)v1[e8] + (float)v2[e8] + (float)v3[e8];
        j += 4;
    }
    for (; j < c; j++) {
        int s = sp[j];
        bf16x8 v = *(const bf16x8*)(base + (size_t)s * 128);
#pragma unroll
        for (int e8 = 0; e8 < 8; e8++) a[e8] += (float)v[e8];
    }
    float iv = 1.0f / (float)(c > 1 ? c : 1);
    bf16x8 o;
#pragma unroll
    for (int e8 = 0; e8 < 8; e8++) o[e8] = (__bf16)(a[e8] * iv);
    *(bf16x8*)(Am + (size_t)node * 128 + sl * 8) = o;
}

// ---------- GEMM z = [Am|Xb] @ Bw^T (+ab), relu, project onto P -> y[node][8] ----------
// Column-split grid: 782 blocks (2 col-halves x 391 row-tiles); ~3 blocks/CU.
// First B-stage issued BEFORE the A-fragment loads so its latency hides there.
__global__ __launch_bounds__(256) void k_gemm(const __bf16* __restrict__ Am,
                                              const __bf16* __restrict__ Xb,
                                              const __bf16* __restrict__ Bw,
                                              const float* __restrict__ ab,
                                              const float* __restrict__ P,
                                              float* __restrict__ y) {
    __shared__ __bf16 Bs[2048 * 8];   // 32 KB
    int tid = threadIdx.x;
    int half = blockIdx.x & 1;        // adjacent blocks share rows -> L2/L3 locality
    int rb   = blockIdx.x >> 1;
    int wave = tid >> 6, lane = tid & 63;
    int r = lane & 15, quad = lane >> 4;
    int row0 = rb * 128 + wave * 32;

    // issue first chunk's B staging NOW; completes under the A-fragment loads
    {
        int chunk = half * 2;
#pragma unroll
        for (int jj = 0; jj < 8; jj++) {
            int g = jj * 256 + tid;
            int gr = g & 15, gq = (g >> 4) & 3;
            int gkk = (g >> 6) & 7;
            int gt = g >> 9;
            const __bf16* src = Bw + (size_t)(chunk * 64 + gt * 16 + gr) * 256 + gkk * 32 + gq * 8;
            __builtin_amdgcn_global_load_lds(
                (const __attribute__((address_space(1))) void*)src,
                (__attribute__((address_space(3))) void*)(Bs + (size_t)g * 8),
                16, 0, 0);
        }
    }

    // A fragments: kk 0..3 -> mean (Am), kk 4..7 -> own (Xb)
    bf16x8 afrag[2][8];
#pragma unroll
    for (int g = 0; g < 2; g++) {
        const __bf16* mp = Am + (size_t)(row0 + g * 16 + r) * 128 + quad * 8;
        const __bf16* op = Xb + (size_t)(row0 + g * 16 + r) * 128 + quad * 8;
#pragma unroll
        for (int kk = 0; kk < 4; kk++) {
            afrag[g][kk]     = *(const bf16x8*)(mp + kk * 32);
            afrag[g][4 + kk] = *(const bf16x8*)(op + kk * 32);
        }
    }

    float part[2][4][4] = {{{0.f}}};

    for (int cc = 0; cc < 2; cc++) {
        int chunk = half * 2 + cc;
        if (cc) {
            __syncthreads();   // all waves done reading Bs chunk 0
#pragma unroll
            for (int jj = 0; jj < 8; jj++) {
                int g = jj * 256 + tid;
                int gr = g & 15, gq = (g >> 4) & 3;
                int gkk = (g >> 6) & 7;
                int gt = g >> 9;
                const __bf16* src = Bw + (size_t)(chunk * 64 + gt * 16 + gr) * 256 + gkk * 32 + gq * 8;
                __builtin_amdgcn_global_load_lds(
                    (const __attribute__((address_space(1))) void*)src,
                    (__attribute__((address_space(3))) void*)(Bs + (size_t)g * 8),
                    16, 0, 0);
            }
        }
        __syncthreads();       // staging visible (barrier drains vmcnt)

        floatx4 acc[2][4];
#pragma unroll
        for (int g = 0; g < 2; g++)
#pragma unroll
            for (int t = 0; t < 4; t++) acc[g][t] = (floatx4){0.f, 0.f, 0.f, 0.f};
#pragma unroll
        for (int kk = 0; kk < 8; kk++) {
#pragma unroll
            for (int t = 0; t < 4; t++) {
                bf16x8 bf = *(const bf16x8*)(Bs + (size_t)((t * 8 + kk) * 64 + lane) * 8);
                acc[0][t] = __builtin_amdgcn_mfma_f32_16x16x32_bf16(afrag[0][kk], bf, acc[0][t], 0, 0, 0);
                acc[1][t] = __builtin_amdgcn_mfma_f32_16x16x32_bf16(afrag[1][kk], bf, acc[1][t], 0, 0, 0);
            }
        }

        // epilogue: h = relu(z + ab[col]); accumulate projection onto P
#pragma unroll
        for (int t = 0; t < 4; t++) {
            int col = chunk * 64 + t * 16 + r;
            float bias = ab[col];
            float4 pv = *(const float4*)(P + col * 4);
#pragma unroll
            for (int g = 0; g < 2; g++)
#pragma unroll
                for (int rr = 0; rr < 4; rr++) {
                    float h = acc[g][t][rr] + bias;
                    h = h > 0.f ? h : 0.f;
                    part[g][rr][0] += h * pv.x; part[g][rr][1] += h * pv.y;
                    part[g][rr][2] += h * pv.z; part[g][rr][3] += h * pv.w;
                }
        }
    }

    // reduce over the 16 col-lanes (r); store 32 rows per wave, this col-half's slot
#pragma unroll
    for (int m = 1; m < 16; m <<= 1)
#pragma unroll
        for (int g = 0; g < 2; g++)
#pragma unroll
            for (int rr = 0; rr < 4; rr++)
#pragma unroll
                for (int j = 0; j < 4; j++)
                    part[g][rr][j] += __shfl_xor(part[g][rr][j], m, 64);
    if (r == 0) {
#pragma unroll
        for (int g = 0; g < 2; g++)
#pragma unroll
            for (int rr = 0; rr < 4; rr++) {
                int row = row0 + g * 16 + quad * 4 + rr;
                float4 o;
                o.x = part[g][rr][0]; o.y = part[g][rr][1];
                o.z = part[g][rr][2]; o.w = part[g][rr][3];
                *(float4*)(y + (size_t)row * 8 + half * 4) = o;
            }
    }
}

// ---------- head: per masked node, slab-walk sum of scalar projections ----------
// y layout per node: [p0l,p1l, s0l,s1l, p0h,p1h, s0h,s1h] (l/h = col-halves)
__global__ void k_head(const int* __restrict__ mask, const int* __restrict__ cnt,
                       const int* __restrict__ slab, const float* __restrict__ y,
                       const float* __restrict__ biasC, float* __restrict__ out) {
    int tid = blockIdx.x * 256 + threadIdx.x;
    int p = tid >> 1, side = tid & 1;
    float res = 0.f;
    if (p < NPAIR) {
        int node = mask[p * 2 + side];
        int c = cnt[node];
        if (c > SLAB) c = SLAB;
        const int* sp = slab + (size_t)node * SLAB;
        float s = 0.f;
        int j = 0;
        for (; j + 4 <= c; j += 4) {
            int4 sa = *(const int4*)(sp + j);
            s += y[(size_t)sa.x * 8 + side] + y[(size_t)sa.x * 8 + 4 + side];
            s += y[(size_t)sa.y * 8 + side] + y[(size_t)sa.y * 8 + 4 + side];
            s += y[(size_t)sa.z * 8 + side] + y[(size_t)sa.z * 8 + 4 + side];
            s += y[(size_t)sa.w * 8 + side] + y[(size_t)sa.w * 8 + 4 + side];
        }
        for (; j < c; j++) {
            int si = sp[j];
            s += y[(size_t)si * 8 + side] + y[(size_t)si * 8 + 4 + side];
        }
        float iv = 1.0f / (float)(c > 1 ? c : 1);
        res = s * iv + y[(size_t)node * 8 + 2 + side] + y[(size_t)node * 8 + 6 + side];
    }
    float other = __shfl_xor(res, 1, 64);
    if (p < NPAIR && side == 0) {
        float z = res + other + *biasC;
        out[p] = 1.f / (1.f + expf(-z));
    }
}

extern "C" void kernel_launch(void* const* d_in, const int* in_sizes, int n_in,
                              void* d_out, int out_size, void* d_ws, size_t ws_size,
                              hipStream_t stream) {
    const float* x_protein = (const float*)d_in[0];
    const float* a_ppi_Wl  = (const float*)d_in[11];
    const float* a_ppi_b   = (const float*)d_in[12];
    const float* a_ppi_Wr  = (const float*)d_in[13];
    const float* b_ppi_Wl  = (const float*)d_in[23];
    const float* b_ppi_b   = (const float*)d_in[24];
    const float* b_ppi_Wr  = (const float*)d_in[25];
    const float* lin_W     = (const float*)d_in[26];
    const float* lin_b     = (const float*)d_in[27];
    const int* ppi_src     = (const int*)d_in[34];
    const int* ppi_dst     = (const int*)d_in[35];
    const int* mask        = (const int*)d_in[36];
    float* out = (float*)d_out;

    char* ws = (char*)d_ws;
    size_t o = 0;
    auto alloc = [&](size_t n) -> char* {
        char* r = ws + o;
        o = (o + n + 511) & ~(size_t)511;
        return r;
    };
    int*    cnt    = (int*)alloc((size_t)NPROT * 4);
    int*    slab   = (int*)alloc((size_t)NPROT * SLAB * 4);
    __bf16* Xb     = (__bf16*)alloc((size_t)NPROT_PAD * 128 * 2);
    __bf16* Am     = (__bf16*)alloc((size_t)NPROT_PAD * 128 * 2);
    __bf16* Bw     = (__bf16*)alloc(256 * 256 * 2);
    float*  P      = (float*)alloc(256 * 4 * 4);
    float*  biasC  = (float*)alloc(4);
    float*  y      = (float*)alloc((size_t)NPROT_PAD * 8 * 4);
    (void)ws_size;

    k_prep<<<6958, 256, 0, stream>>>(x_protein, a_ppi_Wl, a_ppi_Wr, lin_W, lin_b,
                                     b_ppi_Wl, b_ppi_Wr, b_ppi_b,
                                     Xb, Bw, P, biasC, cnt);
    k_link<<<(EPPI + 255) / 256, 256, 0, stream>>>(ppi_src, ppi_dst, cnt, slab);
    k_agg<<<(NPROT + 15) / 16, 256, 0, stream>>>(Xb, cnt, slab, Am);
    k_gemm<<<782, 256, 0, stream>>>(Am, Xb, Bw, a_ppi_b, P, y);
    k_head<<<(2 * NPAIR + 255) / 256, 256, 0, stream>>>(mask, cnt, slab, y, biasC, out);
}